// Round 1
// baseline (1405.860 us; speedup 1.0000x reference)
//
#include <hip/hip_runtime.h>
#include <math.h>

#define T_SEQ 2048
#define DM 512
#define NH 8
#define BATCH 4

// ---------------------------------------------------------------------------
// GEMM: C[m][n] = sum_k X(m,k) * W[n][k] + bias[n]   (K = 512, W row-major NT)
// INMODE 0: X row-major [M][512]
// INMODE 1: X is head-major ctx [bh][t][64]  (m = b*T+t, k = h*64+d)
// OUTMODE 0: scatter to head-major [b][h][t][d]  (n = h*64+d)
// OUTMODE 1: row-major [m][512]
// 64x64 tile, BK=32, 256 threads, 4x4 microtile.
// ---------------------------------------------------------------------------
template <int INMODE, int OUTMODE>
__global__ __launch_bounds__(256)
void gemm512_kernel(const float* __restrict__ X, const float* __restrict__ W,
                    const float* __restrict__ bias, float* __restrict__ out)
{
    __shared__ float As[32][68];   // [k][m]
    __shared__ float Bs[32][68];   // [k][n]
    const int tid  = threadIdx.x;
    const int tx   = tid & 15, ty = tid >> 4;
    const int lrow = tid >> 3;           // 0..31
    const int lc4  = (tid & 7) << 2;     // 0,4,..,28
    const int m0   = blockIdx.x << 6;
    const int n0   = blockIdx.y << 6;

    float c[4][4] = {};

    for (int k0 = 0; k0 < 512; k0 += 32) {
        float4 a0, a1;
        if (INMODE == 0) {
            a0 = *(const float4*)&X[(size_t)(m0 + lrow) * 512 + k0 + lc4];
            a1 = *(const float4*)&X[(size_t)(m0 + lrow + 32) * 512 + k0 + lc4];
        } else {
            const int h = (k0 + lc4) >> 6, d = (k0 + lc4) & 63;
            const int m1 = m0 + lrow, m2 = m1 + 32;
            a0 = *(const float4*)&X[((size_t)((m1 >> 11) * NH + h) * T_SEQ + (m1 & 2047)) * 64 + d];
            a1 = *(const float4*)&X[((size_t)((m2 >> 11) * NH + h) * T_SEQ + (m2 & 2047)) * 64 + d];
        }
        const float4 b0 = *(const float4*)&W[(size_t)(n0 + lrow) * 512 + k0 + lc4];
        const float4 b1 = *(const float4*)&W[(size_t)(n0 + lrow + 32) * 512 + k0 + lc4];

        __syncthreads();
        As[lc4 + 0][lrow] = a0.x; As[lc4 + 1][lrow] = a0.y;
        As[lc4 + 2][lrow] = a0.z; As[lc4 + 3][lrow] = a0.w;
        As[lc4 + 0][lrow + 32] = a1.x; As[lc4 + 1][lrow + 32] = a1.y;
        As[lc4 + 2][lrow + 32] = a1.z; As[lc4 + 3][lrow + 32] = a1.w;
        Bs[lc4 + 0][lrow] = b0.x; Bs[lc4 + 1][lrow] = b0.y;
        Bs[lc4 + 2][lrow] = b0.z; Bs[lc4 + 3][lrow] = b0.w;
        Bs[lc4 + 0][lrow + 32] = b1.x; Bs[lc4 + 1][lrow + 32] = b1.y;
        Bs[lc4 + 2][lrow + 32] = b1.z; Bs[lc4 + 3][lrow + 32] = b1.w;
        __syncthreads();

#pragma unroll
        for (int kk = 0; kk < 32; ++kk) {
            const float4 av = *(const float4*)&As[kk][ty << 2];
            const float4 bv = *(const float4*)&Bs[kk][tx << 2];
            c[0][0] += av.x * bv.x; c[0][1] += av.x * bv.y; c[0][2] += av.x * bv.z; c[0][3] += av.x * bv.w;
            c[1][0] += av.y * bv.x; c[1][1] += av.y * bv.y; c[1][2] += av.y * bv.z; c[1][3] += av.y * bv.w;
            c[2][0] += av.z * bv.x; c[2][1] += av.z * bv.y; c[2][2] += av.z * bv.z; c[2][3] += av.z * bv.w;
            c[3][0] += av.w * bv.x; c[3][1] += av.w * bv.y; c[3][2] += av.w * bv.z; c[3][3] += av.w * bv.w;
        }
    }

    const float4 bvec = *(const float4*)&bias[n0 + (tx << 2)];
#pragma unroll
    for (int i = 0; i < 4; ++i) {
        const int m = m0 + (ty << 2) + i;
        float4 val;
        val.x = c[i][0] + bvec.x; val.y = c[i][1] + bvec.y;
        val.z = c[i][2] + bvec.z; val.w = c[i][3] + bvec.w;
        if (OUTMODE == 0) {
            const int n = n0 + (tx << 2);
            const int h = n >> 6, d = n & 63;
            *(float4*)&out[((size_t)((m >> 11) * NH + h) * T_SEQ + (m & 2047)) * 64 + d] = val;
        } else {
            *(float4*)&out[(size_t)m * 512 + n0 + (tx << 2)] = val;
        }
    }
}

// ---------------------------------------------------------------------------
// S[bh][i][j] = (q[bh][i][:] . k[bh][j][:]) * 0.125   (K = 64)
// ---------------------------------------------------------------------------
__global__ __launch_bounds__(256)
void qk_kernel(const float* __restrict__ q, const float* __restrict__ k,
               float* __restrict__ S)
{
    __shared__ float Qs[64][68];   // [d][i]
    __shared__ float Ks[64][68];   // [d][j]
    const int tid  = threadIdx.x;
    const int tx   = tid & 15, ty = tid >> 4;
    const int lrow = tid >> 3;
    const int lc4  = (tid & 7) << 2;
    const int bh = blockIdx.z;
    const int i0 = blockIdx.y << 6;
    const int j0 = blockIdx.x << 6;
    const float* qb = q + ((size_t)bh * T_SEQ + i0) * 64;
    const float* kb = k + ((size_t)bh * T_SEQ + j0) * 64;

    float4 t0 = *(const float4*)&qb[(size_t)lrow * 64 + lc4];
    float4 t1 = *(const float4*)&qb[(size_t)lrow * 64 + lc4 + 32];
    float4 t2 = *(const float4*)&qb[(size_t)(lrow + 32) * 64 + lc4];
    float4 t3 = *(const float4*)&qb[(size_t)(lrow + 32) * 64 + lc4 + 32];
    Qs[lc4 + 0][lrow] = t0.x; Qs[lc4 + 1][lrow] = t0.y; Qs[lc4 + 2][lrow] = t0.z; Qs[lc4 + 3][lrow] = t0.w;
    Qs[lc4 + 32][lrow] = t1.x; Qs[lc4 + 33][lrow] = t1.y; Qs[lc4 + 34][lrow] = t1.z; Qs[lc4 + 35][lrow] = t1.w;
    Qs[lc4 + 0][lrow + 32] = t2.x; Qs[lc4 + 1][lrow + 32] = t2.y; Qs[lc4 + 2][lrow + 32] = t2.z; Qs[lc4 + 3][lrow + 32] = t2.w;
    Qs[lc4 + 32][lrow + 32] = t3.x; Qs[lc4 + 33][lrow + 32] = t3.y; Qs[lc4 + 34][lrow + 32] = t3.z; Qs[lc4 + 35][lrow + 32] = t3.w;
    t0 = *(const float4*)&kb[(size_t)lrow * 64 + lc4];
    t1 = *(const float4*)&kb[(size_t)lrow * 64 + lc4 + 32];
    t2 = *(const float4*)&kb[(size_t)(lrow + 32) * 64 + lc4];
    t3 = *(const float4*)&kb[(size_t)(lrow + 32) * 64 + lc4 + 32];
    Ks[lc4 + 0][lrow] = t0.x; Ks[lc4 + 1][lrow] = t0.y; Ks[lc4 + 2][lrow] = t0.z; Ks[lc4 + 3][lrow] = t0.w;
    Ks[lc4 + 32][lrow] = t1.x; Ks[lc4 + 33][lrow] = t1.y; Ks[lc4 + 34][lrow] = t1.z; Ks[lc4 + 35][lrow] = t1.w;
    Ks[lc4 + 0][lrow + 32] = t2.x; Ks[lc4 + 1][lrow + 32] = t2.y; Ks[lc4 + 2][lrow + 32] = t2.z; Ks[lc4 + 3][lrow + 32] = t2.w;
    Ks[lc4 + 32][lrow + 32] = t3.x; Ks[lc4 + 33][lrow + 32] = t3.y; Ks[lc4 + 34][lrow + 32] = t3.z; Ks[lc4 + 35][lrow + 32] = t3.w;
    __syncthreads();

    float c[4][4] = {};
#pragma unroll
    for (int d = 0; d < 64; ++d) {
        const float4 av = *(const float4*)&Qs[d][ty << 2];
        const float4 bv = *(const float4*)&Ks[d][tx << 2];
        c[0][0] += av.x * bv.x; c[0][1] += av.x * bv.y; c[0][2] += av.x * bv.z; c[0][3] += av.x * bv.w;
        c[1][0] += av.y * bv.x; c[1][1] += av.y * bv.y; c[1][2] += av.y * bv.z; c[1][3] += av.y * bv.w;
        c[2][0] += av.z * bv.x; c[2][1] += av.z * bv.y; c[2][2] += av.z * bv.z; c[2][3] += av.z * bv.w;
        c[3][0] += av.w * bv.x; c[3][1] += av.w * bv.y; c[3][2] += av.w * bv.z; c[3][3] += av.w * bv.w;
    }

#pragma unroll
    for (int i = 0; i < 4; ++i) {
        float4 val;
        val.x = c[i][0] * 0.125f; val.y = c[i][1] * 0.125f;
        val.z = c[i][2] * 0.125f; val.w = c[i][3] * 0.125f;
        *(float4*)&S[((size_t)bh * T_SEQ + i0 + (ty << 2) + i) * T_SEQ + j0 + (tx << 2)] = val;
    }
}

// ---------------------------------------------------------------------------
// In-place row softmax over 2048 columns; one block per row.
// ---------------------------------------------------------------------------
__global__ __launch_bounds__(256)
void softmax_kernel(float* __restrict__ S)
{
    const size_t row = blockIdx.x;
    float* p = S + row * T_SEQ;
    const int tid = threadIdx.x;
    float4 v0 = *(const float4*)&p[tid * 8];
    float4 v1 = *(const float4*)&p[tid * 8 + 4];

    float m = fmaxf(fmaxf(fmaxf(v0.x, v0.y), fmaxf(v0.z, v0.w)),
                    fmaxf(fmaxf(v1.x, v1.y), fmaxf(v1.z, v1.w)));
#pragma unroll
    for (int off = 32; off; off >>= 1) m = fmaxf(m, __shfl_xor(m, off));
    __shared__ float red[8];
    if ((tid & 63) == 0) red[tid >> 6] = m;
    __syncthreads();
    m = fmaxf(fmaxf(red[0], red[1]), fmaxf(red[2], red[3]));

    float e[8];
    e[0] = __expf(v0.x - m); e[1] = __expf(v0.y - m);
    e[2] = __expf(v0.z - m); e[3] = __expf(v0.w - m);
    e[4] = __expf(v1.x - m); e[5] = __expf(v1.y - m);
    e[6] = __expf(v1.z - m); e[7] = __expf(v1.w - m);
    float s = e[0] + e[1] + e[2] + e[3] + e[4] + e[5] + e[6] + e[7];
#pragma unroll
    for (int off = 32; off; off >>= 1) s += __shfl_xor(s, off);
    if ((tid & 63) == 0) red[4 + (tid >> 6)] = s;
    __syncthreads();
    s = red[4] + red[5] + red[6] + red[7];
    const float inv = 1.0f / s;

    float4 w0, w1;
    w0.x = e[0] * inv; w0.y = e[1] * inv; w0.z = e[2] * inv; w0.w = e[3] * inv;
    w1.x = e[4] * inv; w1.y = e[5] * inv; w1.z = e[6] * inv; w1.w = e[7] * inv;
    *(float4*)&p[tid * 8] = w0;
    *(float4*)&p[tid * 8 + 4] = w1;
}

// ---------------------------------------------------------------------------
// ctx[bh][i][d] = sum_j attn[bh][i][j] * v[bh][j][d]   (N = 64, K = 2048)
// ---------------------------------------------------------------------------
__global__ __launch_bounds__(256)
void pv_kernel(const float* __restrict__ attn, const float* __restrict__ v,
               float* __restrict__ ctx)
{
    __shared__ float As[64][68];   // [j][i]
    __shared__ float Vs[64][68];   // [j][d]
    const int tid  = threadIdx.x;
    const int tx   = tid & 15, ty = tid >> 4;
    const int lrow = tid >> 3;
    const int lc4  = (tid & 7) << 2;
    const int bh = blockIdx.y;
    const int i0 = blockIdx.x << 6;
    const float* ab = attn + ((size_t)bh * T_SEQ + i0) * T_SEQ;
    const float* vb = v + (size_t)bh * T_SEQ * 64;

    float c[4][4] = {};
    for (int j0 = 0; j0 < T_SEQ; j0 += 64) {
        const float4 a00 = *(const float4*)&ab[(size_t)lrow * T_SEQ + j0 + lc4];
        const float4 a01 = *(const float4*)&ab[(size_t)lrow * T_SEQ + j0 + lc4 + 32];
        const float4 a10 = *(const float4*)&ab[(size_t)(lrow + 32) * T_SEQ + j0 + lc4];
        const float4 a11 = *(const float4*)&ab[(size_t)(lrow + 32) * T_SEQ + j0 + lc4 + 32];
        const float4 w0 = *(const float4*)&vb[(size_t)(j0 + lrow) * 64 + lc4];
        const float4 w1 = *(const float4*)&vb[(size_t)(j0 + lrow) * 64 + lc4 + 32];
        const float4 w2 = *(const float4*)&vb[(size_t)(j0 + lrow + 32) * 64 + lc4];
        const float4 w3 = *(const float4*)&vb[(size_t)(j0 + lrow + 32) * 64 + lc4 + 32];

        __syncthreads();
        As[lc4 + 0][lrow] = a00.x; As[lc4 + 1][lrow] = a00.y; As[lc4 + 2][lrow] = a00.z; As[lc4 + 3][lrow] = a00.w;
        As[lc4 + 32][lrow] = a01.x; As[lc4 + 33][lrow] = a01.y; As[lc4 + 34][lrow] = a01.z; As[lc4 + 35][lrow] = a01.w;
        As[lc4 + 0][lrow + 32] = a10.x; As[lc4 + 1][lrow + 32] = a10.y; As[lc4 + 2][lrow + 32] = a10.z; As[lc4 + 3][lrow + 32] = a10.w;
        As[lc4 + 32][lrow + 32] = a11.x; As[lc4 + 33][lrow + 32] = a11.y; As[lc4 + 34][lrow + 32] = a11.z; As[lc4 + 35][lrow + 32] = a11.w;
        *(float4*)&Vs[lrow][lc4] = w0;
        *(float4*)&Vs[lrow][lc4 + 32] = w1;
        *(float4*)&Vs[lrow + 32][lc4] = w2;
        *(float4*)&Vs[lrow + 32][lc4 + 32] = w3;
        __syncthreads();

#pragma unroll
        for (int kk = 0; kk < 64; ++kk) {
            const float4 av = *(const float4*)&As[kk][ty << 2];
            const float4 bv = *(const float4*)&Vs[kk][tx << 2];
            c[0][0] += av.x * bv.x; c[0][1] += av.x * bv.y; c[0][2] += av.x * bv.z; c[0][3] += av.x * bv.w;
            c[1][0] += av.y * bv.x; c[1][1] += av.y * bv.y; c[1][2] += av.y * bv.z; c[1][3] += av.y * bv.w;
            c[2][0] += av.z * bv.x; c[2][1] += av.z * bv.y; c[2][2] += av.z * bv.z; c[2][3] += av.z * bv.w;
            c[3][0] += av.w * bv.x; c[3][1] += av.w * bv.y; c[3][2] += av.w * bv.z; c[3][3] += av.w * bv.w;
        }
    }

#pragma unroll
    for (int i = 0; i < 4; ++i) {
        float4 val;
        val.x = c[i][0]; val.y = c[i][1]; val.z = c[i][2]; val.w = c[i][3];
        *(float4*)&ctx[((size_t)bh * T_SEQ + i0 + (ty << 2) + i) * 64 + (tx << 2)] = val;
    }
}

extern "C" void kernel_launch(void* const* d_in, const int* in_sizes, int n_in,
                              void* d_out, int out_size, void* d_ws, size_t ws_size,
                              hipStream_t stream) {
    const float* Q   = (const float*)d_in[0];
    const float* K   = (const float*)d_in[1];
    const float* V   = (const float*)d_in[2];
    const float* W_q = (const float*)d_in[3];
    const float* b_q = (const float*)d_in[4];
    const float* W_k = (const float*)d_in[5];
    const float* b_k = (const float*)d_in[6];
    const float* W_v = (const float*)d_in[7];
    const float* b_v = (const float*)d_in[8];
    const float* W_o = (const float*)d_in[9];
    const float* b_o = (const float*)d_in[10];

    float* out  = (float*)d_out;
    float* attn = out + (size_t)BATCH * T_SEQ * DM;   // output 1 region; also S scratch

    const size_t HSZ = (size_t)BATCH * NH * T_SEQ * 64;  // 4,194,304 floats
    float* qh  = (float*)d_ws;          // [bh][t][d]
    float* kh  = qh + HSZ;
    float* vh  = qh + 2 * HSZ;
    float* ctx = qh;                    // reuse q slot (dead after qk_kernel)

    const dim3 blk(256);
    const dim3 gProj(128, 8);

    gemm512_kernel<0, 0><<<gProj, blk, 0, stream>>>(Q, W_q, b_q, qh);
    gemm512_kernel<0, 0><<<gProj, blk, 0, stream>>>(K, W_k, b_k, kh);
    gemm512_kernel<0, 0><<<gProj, blk, 0, stream>>>(V, W_v, b_v, vh);

    qk_kernel<<<dim3(32, 32, 32), blk, 0, stream>>>(qh, kh, attn);
    softmax_kernel<<<dim3(65536), blk, 0, stream>>>(attn);
    pv_kernel<<<dim3(32, 32), blk, 0, stream>>>(attn, vh, ctx);

    gemm512_kernel<1, 1><<<gProj, blk, 0, stream>>>(ctx, W_o, b_o, out);
}

// Round 2
// 803.124 us; speedup vs baseline: 1.7505x; 1.7505x over previous
//
#include <hip/hip_runtime.h>
#include <math.h>

#define T_SEQ 2048
#define DM 512
#define NH 8
#define BATCH 4

typedef _Float16 f16;
typedef _Float16 f16x8 __attribute__((ext_vector_type(8)));
typedef _Float16 f16x4 __attribute__((ext_vector_type(4)));
typedef float f32x4 __attribute__((ext_vector_type(4)));

__device__ __forceinline__ f32x4 mfma16(f16x8 a, f16x8 b, f32x4 c) {
    return __builtin_amdgcn_mfma_f32_16x16x32_f16(a, b, c, 0, 0, 0);
}

// ---------------------------------------------------------------------------
// Projection GEMM: C[m][n] = sum_k X(m,k)*W[n][k] + bias[n], M=8192 N=512 K=512
// XMODE 0: X fp32 row-major [M][512];  XMODE 1: X f16 row-major [M][512]
// OUTMODE 0: f16 head-major [bh][t][64], value scaled by `scale`
// OUTMODE 1: f16 V-transposed [bh][d][t]
// OUTMODE 2: fp32 row-major [M][512]   (final output)
// 64x64 tile, BK=64, 256 threads / 4 waves, each wave 32x32 via 16x16x32 MFMA.
// ---------------------------------------------------------------------------
template <int XMODE, int OUTMODE>
__global__ __launch_bounds__(256)
void proj_kernel(const void* __restrict__ Xv, const float* __restrict__ W,
                 const float* __restrict__ bias, void* __restrict__ outv,
                 float scale)
{
    __shared__ char smem[18432];
    f16 (*As)[72] = (f16(*)[72])smem;            // [m][k] pitch 72 f16
    f16 (*Bs)[72] = (f16(*)[72])(smem + 9216);   // [n][k]

    const int tid  = threadIdx.x;
    const int lane = tid & 63;
    const int w    = tid >> 6;
    const int m    = lane & 15;       // MFMA row/col-in-fragment index
    const int quad = lane >> 4;
    const int m_off = (w & 1) * 32;
    const int n_off = (w >> 1) * 32;
    const int m0 = blockIdx.x << 6;
    const int n0 = blockIdx.y << 6;

    const int r = tid >> 2;           // staging row 0..63
    const int c = (tid & 3) << 4;     // staging col 0,16,32,48

    f32x4 acc[2][2] = {};

    for (int k0 = 0; k0 < 512; k0 += 64) {
        __syncthreads();
        // stage A
        if (XMODE == 0) {
            const float* xr = (const float*)Xv + (size_t)(m0 + r) * 512 + k0 + c;
            float4 x0 = ((const float4*)xr)[0], x1 = ((const float4*)xr)[1];
            float4 x2 = ((const float4*)xr)[2], x3 = ((const float4*)xr)[3];
            f16x8 h0, h1;
            h0[0] = x0.x; h0[1] = x0.y; h0[2] = x0.z; h0[3] = x0.w;
            h0[4] = x1.x; h0[5] = x1.y; h0[6] = x1.z; h0[7] = x1.w;
            h1[0] = x2.x; h1[1] = x2.y; h1[2] = x2.z; h1[3] = x2.w;
            h1[4] = x3.x; h1[5] = x3.y; h1[6] = x3.z; h1[7] = x3.w;
            *(f16x8*)&As[r][c] = h0; *(f16x8*)&As[r][c + 8] = h1;
        } else {
            const f16x8* xr = (const f16x8*)((const f16*)Xv + (size_t)(m0 + r) * 512 + k0 + c);
            *(f16x8*)&As[r][c] = xr[0]; *(f16x8*)&As[r][c + 8] = xr[1];
        }
        // stage B (W fp32 [n][k])
        {
            const float* wr = W + (size_t)(n0 + r) * 512 + k0 + c;
            float4 x0 = ((const float4*)wr)[0], x1 = ((const float4*)wr)[1];
            float4 x2 = ((const float4*)wr)[2], x3 = ((const float4*)wr)[3];
            f16x8 h0, h1;
            h0[0] = x0.x; h0[1] = x0.y; h0[2] = x0.z; h0[3] = x0.w;
            h0[4] = x1.x; h0[5] = x1.y; h0[6] = x1.z; h0[7] = x1.w;
            h1[0] = x2.x; h1[1] = x2.y; h1[2] = x2.z; h1[3] = x2.w;
            h1[4] = x3.x; h1[5] = x3.y; h1[6] = x3.z; h1[7] = x3.w;
            *(f16x8*)&Bs[r][c] = h0; *(f16x8*)&Bs[r][c + 8] = h1;
        }
        __syncthreads();

#pragma unroll
        for (int kk = 0; kk < 64; kk += 32) {
            f16x8 a0 = *(const f16x8*)&As[m_off + m][kk + quad * 8];
            f16x8 a1 = *(const f16x8*)&As[m_off + 16 + m][kk + quad * 8];
            f16x8 b0 = *(const f16x8*)&Bs[n_off + m][kk + quad * 8];
            f16x8 b1 = *(const f16x8*)&Bs[n_off + 16 + m][kk + quad * 8];
            acc[0][0] = mfma16(a0, b0, acc[0][0]);
            acc[0][1] = mfma16(a0, b1, acc[0][1]);
            acc[1][0] = mfma16(a1, b0, acc[1][0]);
            acc[1][1] = mfma16(a1, b1, acc[1][1]);
        }
    }

    float biasn[2];
    biasn[0] = bias[n0 + n_off + m];
    biasn[1] = bias[n0 + n_off + 16 + m];

    const int b = m0 >> 11;           // batch index (tile never crosses batch)
    const int h = n0 >> 6;            // head index  (N-tile == one head)

    if (OUTMODE == 0) {
        __syncthreads();
        f16 (*Cs16)[72] = (f16(*)[72])smem;   // [m][n] reuse
#pragma unroll
        for (int bm = 0; bm < 2; ++bm)
#pragma unroll
            for (int bn = 0; bn < 2; ++bn)
#pragma unroll
                for (int reg = 0; reg < 4; ++reg)
                    Cs16[m_off + bm * 16 + quad * 4 + reg][n_off + bn * 16 + m] =
                        (f16)((acc[bm][bn][reg] + biasn[bn]) * scale);
        __syncthreads();
        f16* outp = (f16*)outv;
        const size_t row = ((size_t)(b * NH + h) * T_SEQ + ((m0 + r) & 2047)) * 64 + c;
        *(f16x8*)&outp[row]     = *(const f16x8*)&Cs16[r][c];
        *(f16x8*)&outp[row + 8] = *(const f16x8*)&Cs16[r][c + 8];
    } else if (OUTMODE == 1) {
        f16* vt = (f16*)outv;
#pragma unroll
        for (int bm = 0; bm < 2; ++bm)
#pragma unroll
            for (int bn = 0; bn < 2; ++bn) {
                const int tg = (m0 + m_off + bm * 16 + quad * 4) & 2047;
                const int dd = n_off + bn * 16 + m;
                f16x4 v4;
#pragma unroll
                for (int reg = 0; reg < 4; ++reg)
                    v4[reg] = (f16)(acc[bm][bn][reg] + biasn[bn]);
                *(f16x4*)&vt[((size_t)(b * NH + h) * 64 + dd) * T_SEQ + tg] = v4;
            }
    } else {
        __syncthreads();
        float (*Cs)[68] = (float(*)[68])smem;
#pragma unroll
        for (int bm = 0; bm < 2; ++bm)
#pragma unroll
            for (int bn = 0; bn < 2; ++bn)
#pragma unroll
                for (int reg = 0; reg < 4; ++reg)
                    Cs[m_off + bm * 16 + quad * 4 + reg][n_off + bn * 16 + m] =
                        acc[bm][bn][reg] + biasn[bn];
        __syncthreads();
        float* outp = (float*)outv + (size_t)(m0 + r) * 512 + n0 + c;
        ((float4*)outp)[0] = *(const float4*)&Cs[r][c];
        ((float4*)outp)[1] = *(const float4*)&Cs[r][c + 4];
        ((float4*)outp)[2] = *(const float4*)&Cs[r][c + 8];
        ((float4*)outp)[3] = *(const float4*)&Cs[r][c + 12];
    }
}

// ---------------------------------------------------------------------------
// Fused attention: per (bh, 64-row i-tile). Two passes over K-tiles:
//   pass1: S = q k^T (MFMA), online row max/sum
//   pass2: recompute S (bitwise identical), p = exp(s-m)/l, write attn fp32,
//          p -> LDS f16 -> A-fragments, O += P V (MFMA on vT tiles)
// ---------------------------------------------------------------------------
__global__ __launch_bounds__(256)
void attn_kernel(const f16* __restrict__ qh, const f16* __restrict__ kh,
                 const f16* __restrict__ vt, float* __restrict__ attn,
                 f16* __restrict__ ctx)
{
    __shared__ f16 q_s[64][72];
    __shared__ f16 k_s[64][72];
    __shared__ f16 vt_s[64][72];
    __shared__ f16 p_s[4][16][72];

    const int tid  = threadIdx.x;
    const int lane = tid & 63;
    const int w    = tid >> 6;
    const int m    = lane & 15;
    const int quad = lane >> 4;
    const int bh   = blockIdx.y;
    const int i0   = blockIdx.x << 6;

    const int r = tid >> 2;
    const int c = (tid & 3) << 4;

    // load q tile (scaled by 1/8 already)
    {
        const f16x8* src = (const f16x8*)&qh[((size_t)bh * T_SEQ + i0 + r) * 64 + c];
        *(f16x8*)&q_s[r][c] = src[0]; *(f16x8*)&q_s[r][c + 8] = src[1];
    }

    float mrow[4], lrow[4];
#pragma unroll
    for (int i = 0; i < 4; ++i) { mrow[i] = -1e30f; lrow[i] = 0.f; }

    // ---- pass 1: max/sum ----
    for (int j0 = 0; j0 < T_SEQ; j0 += 64) {
        __syncthreads();
        {
            const f16x8* src = (const f16x8*)&kh[((size_t)bh * T_SEQ + j0 + r) * 64 + c];
            *(f16x8*)&k_s[r][c] = src[0]; *(f16x8*)&k_s[r][c + 8] = src[1];
        }
        __syncthreads();

        f32x4 s[4] = {};
#pragma unroll
        for (int kk = 0; kk < 64; kk += 32) {
            f16x8 a = *(const f16x8*)&q_s[w * 16 + m][kk + quad * 8];
#pragma unroll
            for (int bn = 0; bn < 4; ++bn) {
                f16x8 b = *(const f16x8*)&k_s[bn * 16 + m][kk + quad * 8];
                s[bn] = mfma16(a, b, s[bn]);
            }
        }
#pragma unroll
        for (int reg = 0; reg < 4; ++reg) {
            float tm = fmaxf(fmaxf(s[0][reg], s[1][reg]), fmaxf(s[2][reg], s[3][reg]));
            tm = fmaxf(tm, __shfl_xor(tm, 1));
            tm = fmaxf(tm, __shfl_xor(tm, 2));
            tm = fmaxf(tm, __shfl_xor(tm, 4));
            tm = fmaxf(tm, __shfl_xor(tm, 8));
            const float mn = fmaxf(mrow[reg], tm);
            float ts = __expf(s[0][reg] - mn) + __expf(s[1][reg] - mn) +
                       __expf(s[2][reg] - mn) + __expf(s[3][reg] - mn);
            ts += __shfl_xor(ts, 1);
            ts += __shfl_xor(ts, 2);
            ts += __shfl_xor(ts, 4);
            ts += __shfl_xor(ts, 8);
            lrow[reg] = lrow[reg] * __expf(mrow[reg] - mn) + ts;
            mrow[reg] = mn;
        }
    }

    float inv_l[4];
#pragma unroll
    for (int i = 0; i < 4; ++i) inv_l[i] = 1.0f / lrow[i];

    // ---- pass 2: write probs + PV ----
    f32x4 o[4] = {};
    for (int j0 = 0; j0 < T_SEQ; j0 += 64) {
        __syncthreads();
        {
            const f16x8* src = (const f16x8*)&kh[((size_t)bh * T_SEQ + j0 + r) * 64 + c];
            *(f16x8*)&k_s[r][c] = src[0]; *(f16x8*)&k_s[r][c + 8] = src[1];
            const f16x8* vsrc = (const f16x8*)&vt[((size_t)bh * 64 + r) * T_SEQ + j0 + c];
            *(f16x8*)&vt_s[r][c] = vsrc[0]; *(f16x8*)&vt_s[r][c + 8] = vsrc[1];
        }
        __syncthreads();

        f32x4 s[4] = {};
#pragma unroll
        for (int kk = 0; kk < 64; kk += 32) {
            f16x8 a = *(const f16x8*)&q_s[w * 16 + m][kk + quad * 8];
#pragma unroll
            for (int bn = 0; bn < 4; ++bn) {
                f16x8 b = *(const f16x8*)&k_s[bn * 16 + m][kk + quad * 8];
                s[bn] = mfma16(a, b, s[bn]);
            }
        }

        const size_t arow_base = ((size_t)bh * T_SEQ + i0 + w * 16 + quad * 4) * T_SEQ + j0;
#pragma unroll
        for (int reg = 0; reg < 4; ++reg) {
            float* arow = attn + arow_base + (size_t)reg * T_SEQ;
#pragma unroll
            for (int bn = 0; bn < 4; ++bn) {
                const float p = __expf(s[bn][reg] - mrow[reg]) * inv_l[reg];
                arow[bn * 16 + m] = p;
                p_s[w][quad * 4 + reg][bn * 16 + m] = (f16)p;
            }
        }

        // PV: same-wave LDS write->read is in-order; no barrier needed
#pragma unroll
        for (int kk = 0; kk < 64; kk += 32) {
            f16x8 pa = *(const f16x8*)&p_s[w][m][kk + quad * 8];
#pragma unroll
            for (int bd = 0; bd < 4; ++bd) {
                f16x8 vb = *(const f16x8*)&vt_s[bd * 16 + m][kk + quad * 8];
                o[bd] = mfma16(pa, vb, o[bd]);
            }
        }
    }

    // ---- epilogue: ctx f16 row-major [b*T + t][512] ----
    __syncthreads();
#pragma unroll
    for (int bd = 0; bd < 4; ++bd)
#pragma unroll
        for (int reg = 0; reg < 4; ++reg)
            q_s[w * 16 + quad * 4 + reg][bd * 16 + m] = (f16)(o[bd][reg]);
    __syncthreads();

    const int b = bh >> 3, h = bh & 7;
    const size_t row = ((size_t)b * T_SEQ + i0 + r) * 512 + h * 64 + c;
    *(f16x8*)&ctx[row]     = *(const f16x8*)&q_s[r][c];
    *(f16x8*)&ctx[row + 8] = *(const f16x8*)&q_s[r][c + 8];
}

extern "C" void kernel_launch(void* const* d_in, const int* in_sizes, int n_in,
                              void* d_out, int out_size, void* d_ws, size_t ws_size,
                              hipStream_t stream) {
    const float* Q   = (const float*)d_in[0];
    const float* K   = (const float*)d_in[1];
    const float* V   = (const float*)d_in[2];
    const float* W_q = (const float*)d_in[3];
    const float* b_q = (const float*)d_in[4];
    const float* W_k = (const float*)d_in[5];
    const float* b_k = (const float*)d_in[6];
    const float* W_v = (const float*)d_in[7];
    const float* b_v = (const float*)d_in[8];
    const float* W_o = (const float*)d_in[9];
    const float* b_o = (const float*)d_in[10];

    float* out  = (float*)d_out;
    float* attn = out + (size_t)BATCH * T_SEQ * DM;

    const size_t HSZ = (size_t)BATCH * NH * T_SEQ * 64;  // 4,194,304
    f16* qh   = (f16*)d_ws;
    f16* khp  = qh + HSZ;
    f16* vtp  = khp + HSZ;
    f16* ctxh = vtp + HSZ;

    const dim3 blk(256);
    const dim3 gProj(128, 8);

    proj_kernel<0, 0><<<gProj, blk, 0, stream>>>(Q, W_q, b_q, qh, 0.125f);
    proj_kernel<0, 0><<<gProj, blk, 0, stream>>>(K, W_k, b_k, khp, 1.0f);
    proj_kernel<0, 1><<<gProj, blk, 0, stream>>>(V, W_v, b_v, vtp, 1.0f);

    attn_kernel<<<dim3(32, 32), blk, 0, stream>>>(qh, khp, vtp, attn, ctxh);

    proj_kernel<1, 2><<<gProj, blk, 0, stream>>>(ctxh, W_o, b_o, out, 1.0f);
}